// Round 4
// baseline (111.078 us; speedup 1.0000x reference)
//
#include <hip/hip_runtime.h>
#include <math.h>

#define BB 128
#define NN 512
#define CHUNKS 8
#define RPB (NN / CHUNKS)   // 64 rows per block
#define RPW (RPB / 4)       // 16 rows per wave
#define GRID (BB * CHUNKS)
#define EPSF 1e-7f
#define ONEP (1.0f + EPSF)
#define TWOEPS (2.0f * EPSF)

// One block = (batch b, 64-row chunk). 256 threads = 4 waves, 16 rows/wave,
// 4 rows per iteration for ILP on the shuffle/rcp/log chains.
// Identities (pred ~ N(0,1) -> no max-subtraction needed):
//   e_j = exp(pred_j) row-independent, computed once per block.
//   S_i = sum_{T_j >= T_i} e_j ;  part1 = log(S_i) - pred_i
//   part2 = sum_all_j -log(q_ij) + log(q_ii),  q = max(1+eps - e_j/S_i, 2eps)
//   per lane: product of 8 q's then ONE log (prod >= ~e^-17, no underflow).
// Final divide fused via last-block ticket (ws[2] = ticket counter).
__global__ __launch_bounds__(256, 4) void cox_main(const float* __restrict__ pred,
                                                   const float* __restrict__ target,
                                                   const int* __restrict__ valid,
                                                   float* __restrict__ ws,
                                                   float* __restrict__ out) {
    __shared__ float s_e[NN];    // exp(pred)
    __shared__ float s_tm[NN];   // masked target
    __shared__ float s_p[NN];    // pred
    __shared__ float s_is[NN];   // invS per row (this block's rows only)
    __shared__ float s_max[4];
    __shared__ float s_cnt[4];
    __shared__ float s_acc[4];

    const int b     = blockIdx.x / CHUNKS;
    const int chunk = blockIdx.x % CHUNKS;
    const int tid   = threadIdx.x;
    const int lane  = tid & 63;
    const int wave  = tid >> 6;

    // ---- stage inputs, fold batch max + valid count ----
    float lmax = -1.0f, lcnt = 0.0f;
    #pragma unroll
    for (int k = 0; k < NN / 256; ++k) {
        int j = tid + 256 * k;
        float p = pred[b * NN + j];
        float t = target[b * NN + j];
        int   v = valid[b * NN + j];
        float tm = v ? t : -1.0f;
        s_p[j]  = p;
        s_e[j]  = __expf(p);
        s_tm[j] = tm;
        lmax = fmaxf(lmax, tm);
        lcnt += v ? 1.0f : 0.0f;
    }
    #pragma unroll
    for (int off = 32; off; off >>= 1) {
        lmax = fmaxf(lmax, __shfl_xor(lmax, off, 64));
        lcnt += __shfl_xor(lcnt, off, 64);
    }
    if (lane == 0) { s_max[wave] = lmax; s_cnt[wave] = lcnt; }
    __syncthreads();
    const float bmax = fmaxf(fmaxf(s_max[0], s_max[1]), fmaxf(s_max[2], s_max[3]));
    const float bcnt = s_cnt[0] + s_cnt[1] + s_cnt[2] + s_cnt[3];
    const float batch_valid = (bcnt >= 2.0f) ? 1.0f : 0.0f;

    // ---- preload lane-owned columns into registers (once per block) ----
    float tj[8], e0[8];
    #pragma unroll
    for (int k = 0; k < 8; ++k) {
        tj[k] = s_tm[lane + 64 * k];
        e0[k] = s_e[lane + 64 * k];
    }

    // ---- O(N^2) row loop, 4 rows per iteration for ILP ----
    float acc = 0.0f;
    const int row0 = chunk * RPB + wave * RPW;
    for (int r0 = 0; r0 < RPW; r0 += 4) {
        const int i0 = row0 + r0;
        float Ti[4], S[4], prod[4], elim[4], invS[4];
        float em[4][8];
        #pragma unroll
        for (int rr = 0; rr < 4; ++rr) {
            Ti[rr]   = s_tm[i0 + rr];
            elim[rr] = (Ti[rr] > 0.0f && Ti[rr] < bmax) ? 1.0f : 0.0f;
            S[rr]    = 0.0f;
            prod[rr] = 1.0f;
        }
        #pragma unroll
        for (int k = 0; k < 8; ++k) {
            #pragma unroll
            for (int rr = 0; rr < 4; ++rr) {
                float x = (tj[k] >= Ti[rr]) ? e0[k] : 0.0f;
                em[rr][k] = x;
                S[rr] += x;
            }
        }
        #pragma unroll
        for (int off = 32; off; off >>= 1) {
            #pragma unroll
            for (int rr = 0; rr < 4; ++rr)
                S[rr] += __shfl_xor(S[rr], off, 64);
        }
        #pragma unroll
        for (int rr = 0; rr < 4; ++rr)
            invS[rr] = __builtin_amdgcn_rcpf(S[rr]);
        if (lane == 0) {
            #pragma unroll
            for (int rr = 0; rr < 4; ++rr) s_is[i0 + rr] = invS[rr];
        }
        #pragma unroll
        for (int k = 0; k < 8; ++k) {
            #pragma unroll
            for (int rr = 0; rr < 4; ++rr)
                prod[rr] *= fmaxf(fmaf(-em[rr][k], invS[rr], ONEP), TWOEPS);
        }
        #pragma unroll
        for (int rr = 0; rr < 4; ++rr)
            acc -= elim[rr] * __logf(prod[rr]);
    }

    // ---- per-row epilogue: part1 + diagonal correction (same wave's rows) ----
    if (lane < RPW) {
        const int i = row0 + lane;
        const float Ti = s_tm[i];
        if (Ti > 0.0f && Ti < bmax) {
            float invS = s_is[i];
            float part1 = -__logf(invS) - s_p[i];
            float pii = s_e[i] * invS;
            float qi = fmaxf(ONEP - pii, TWOEPS);
            acc += part1 + __logf(qi);
        }
    }

    // ---- block reduce, commit, last-block finalize ----
    #pragma unroll
    for (int off = 32; off; off >>= 1) acc += __shfl_xor(acc, off, 64);
    if (lane == 0) s_acc[wave] = acc;
    __syncthreads();
    if (tid == 0) {
        float tot = (s_acc[0] + s_acc[1] + s_acc[2] + s_acc[3]) * batch_valid;
        atomicAdd(ws, tot);
        if (chunk == 0) atomicAdd(ws + 1, batch_valid);
        __threadfence();  // make the sums visible before taking a ticket
        unsigned int ticket = atomicAdd((unsigned int*)ws + 2, 1u);
        if (ticket == GRID - 1) {
            // coherent reads via atomic RMW (returns current value)
            float total = atomicAdd(ws, 0.0f);
            float cnt   = atomicAdd(ws + 1, 0.0f);
            out[0] = total / fmaxf(cnt, 1.0f);
        }
    }
}

extern "C" void kernel_launch(void* const* d_in, const int* in_sizes, int n_in,
                              void* d_out, int out_size, void* d_ws, size_t ws_size,
                              hipStream_t stream) {
    const float* pred   = (const float*)d_in[0];
    const float* target = (const float*)d_in[1];
    const int*   valid  = (const int*)d_in[2];
    float* out = (float*)d_out;
    float* ws  = (float*)d_ws;

    hipMemsetAsync(ws, 0, 16, stream);  // ws[0]=sum, ws[1]=valid count, ws[2]=ticket
    cox_main<<<GRID, 256, 0, stream>>>(pred, target, valid, ws, out);
}

// Round 5
// 92.102 us; speedup vs baseline: 1.2060x; 1.2060x over previous
//
#include <hip/hip_runtime.h>
#include <math.h>

#define BB 128
#define NN 512
#define CHUNKS 16
#define RPB (NN / CHUNKS)   // 32 rows per block
#define RPW (RPB / 4)       // 8 rows per wave
#define EPSF 1e-7f
#define ONEP (1.0f + EPSF)
#define TWOEPS (2.0f * EPSF)

// One block = (batch b, 32-row chunk). 256 threads = 4 waves, 8 rows/wave.
// Grid = 128*16 = 2048 blocks = 8192 waves -> fills all 256CU x 32 wave slots.
// Identities (pred ~ N(0,1) -> no max-subtraction needed):
//   e_j = exp(pred_j) row-independent, computed once per block.
//   S_i = sum_{T_j >= T_i} e_j ;  part1 = log(S_i) - pred_i
//   part2 = sum_all_j -log(q_ij) + log(q_ii),  q = max(1+eps - e_j/S_i, 2eps)
//   per lane: product of 8 q's then ONE log (prod >= ~e^-17, no underflow).
// NOTE: no __threadfence() anywhere — a device-scope fence forces L2
// writeback/invalidate of the 268MB poisoned ws (R4: +84MB HBM, +30us).
__global__ __launch_bounds__(256) void cox_main(const float* __restrict__ pred,
                                                const float* __restrict__ target,
                                                const int* __restrict__ valid,
                                                float* __restrict__ ws) {
    __shared__ float s_e[NN];    // exp(pred)
    __shared__ float s_tm[NN];   // masked target
    __shared__ float s_p[NN];    // pred
    __shared__ float s_is[NN];   // invS per row (this block's rows only)
    __shared__ float s_max[4];
    __shared__ float s_cnt[4];
    __shared__ float s_acc[4];

    const int b     = blockIdx.x / CHUNKS;
    const int chunk = blockIdx.x % CHUNKS;
    const int tid   = threadIdx.x;
    const int lane  = tid & 63;
    const int wave  = tid >> 6;

    // ---- stage inputs, fold batch max + valid count ----
    float lmax = -1.0f, lcnt = 0.0f;
    #pragma unroll
    for (int k = 0; k < NN / 256; ++k) {
        int j = tid + 256 * k;
        float p = pred[b * NN + j];
        float t = target[b * NN + j];
        int   v = valid[b * NN + j];
        float tm = v ? t : -1.0f;
        s_p[j]  = p;
        s_e[j]  = __expf(p);
        s_tm[j] = tm;
        lmax = fmaxf(lmax, tm);
        lcnt += v ? 1.0f : 0.0f;
    }
    #pragma unroll
    for (int off = 32; off; off >>= 1) {
        lmax = fmaxf(lmax, __shfl_xor(lmax, off, 64));
        lcnt += __shfl_xor(lcnt, off, 64);
    }
    if (lane == 0) { s_max[wave] = lmax; s_cnt[wave] = lcnt; }
    __syncthreads();
    const float bmax = fmaxf(fmaxf(s_max[0], s_max[1]), fmaxf(s_max[2], s_max[3]));
    const float bcnt = s_cnt[0] + s_cnt[1] + s_cnt[2] + s_cnt[3];
    const float batch_valid = (bcnt >= 2.0f) ? 1.0f : 0.0f;

    // ---- preload lane-owned columns into registers (once per block) ----
    float tj[8], e0[8];
    #pragma unroll
    for (int k = 0; k < 8; ++k) {
        tj[k] = s_tm[lane + 64 * k];
        e0[k] = s_e[lane + 64 * k];
    }

    // ---- O(N^2) row loop ----
    float acc = 0.0f;
    const int row0 = chunk * RPB + wave * RPW;
    for (int r = 0; r < RPW; ++r) {
        const int i = row0 + r;
        const float Ti = s_tm[i];                   // wave-uniform broadcast
        if (!(Ti > 0.0f && Ti < bmax)) continue;    // not eliminated (uniform)

        float em[8];
        float S = 0.0f;
        #pragma unroll
        for (int k = 0; k < 8; ++k) {
            float x = (tj[k] >= Ti) ? e0[k] : 0.0f;
            em[k] = x;
            S += x;
        }
        #pragma unroll
        for (int off = 32; off; off >>= 1) S += __shfl_xor(S, off, 64);
        const float invS = __builtin_amdgcn_rcpf(S);
        if (lane == 0) s_is[i] = invS;

        float prod = 1.0f;
        #pragma unroll
        for (int k = 0; k < 8; ++k)
            prod *= fmaxf(fmaf(-em[k], invS, ONEP), TWOEPS);
        acc -= __logf(prod);
    }

    // ---- per-row epilogue: part1 + diagonal correction (same wave's rows) ----
    if (lane < RPW) {
        const int i = row0 + lane;
        const float Ti = s_tm[i];
        if (Ti > 0.0f && Ti < bmax) {
            float invS = s_is[i];
            float part1 = -__logf(invS) - s_p[i];
            float pii = s_e[i] * invS;
            float qi = fmaxf(ONEP - pii, TWOEPS);
            acc += part1 + __logf(qi);
        }
    }

    // ---- block reduce and commit ----
    #pragma unroll
    for (int off = 32; off; off >>= 1) acc += __shfl_xor(acc, off, 64);
    if (lane == 0) s_acc[wave] = acc;
    __syncthreads();
    if (tid == 0) {
        float tot = (s_acc[0] + s_acc[1] + s_acc[2] + s_acc[3]) * batch_valid;
        atomicAdd(ws, tot);
        if (chunk == 0) atomicAdd(ws + 1, batch_valid);
    }
}

__global__ void cox_final(const float* __restrict__ ws, float* __restrict__ out) {
    out[0] = ws[0] / fmaxf(ws[1], 1.0f);
}

extern "C" void kernel_launch(void* const* d_in, const int* in_sizes, int n_in,
                              void* d_out, int out_size, void* d_ws, size_t ws_size,
                              hipStream_t stream) {
    const float* pred   = (const float*)d_in[0];
    const float* target = (const float*)d_in[1];
    const int*   valid  = (const int*)d_in[2];
    float* out = (float*)d_out;
    float* ws  = (float*)d_ws;

    hipMemsetAsync(ws, 0, 2 * sizeof(float), stream);
    cox_main<<<BB * CHUNKS, 256, 0, stream>>>(pred, target, valid, ws);
    cox_final<<<1, 1, 0, stream>>>(ws, out);
}

// Round 6
// 69.288 us; speedup vs baseline: 1.6031x; 1.3293x over previous
//
#include <hip/hip_runtime.h>
#include <math.h>

#define BB 128
#define NN 512
#define CHUNKS 8
#define RPB (NN / CHUNKS)   // 64 rows per block
#define RPW (RPB / 4)       // 16 rows per wave
#define GRID (BB * CHUNKS)
#define EPSF 1e-7f
#define ONEP (1.0f + EPSF)
#define TWOEPS (2.0f * EPSF)

// One block = (batch b, 64-row chunk). 256 threads = 4 waves, 16 rows/wave.
// Identities (pred ~ N(0,1) -> no max-subtraction needed):
//   e_j = exp(pred_j) row-independent, computed once per block.
//   S_i = sum_{T_j >= T_i} e_j ;  part1 = log(S_i) - pred_i
//   part2 = sum_all_j -log(q_ij) + log(q_ii),  q = max(1+eps - e_j/S_i, 2eps)
//   per lane: product of 8 q's then ONE log (prod >= ~e^-17, no underflow).
// Partials are WRITTEN to distinct ws slots (no memset, no atomics, no fence):
//   ws[0..GRID)        block partial sums (already scaled by batch_valid)
//   ws[GRID..GRID+BB)  per-batch valid flag (written by chunk==0 block)
// Kernel-boundary release makes these visible to cox_final on the same stream.
__global__ __launch_bounds__(256) void cox_main(const float* __restrict__ pred,
                                                const float* __restrict__ target,
                                                const int* __restrict__ valid,
                                                float* __restrict__ ws) {
    __shared__ float s_e[NN];    // exp(pred)
    __shared__ float s_tm[NN];   // masked target
    __shared__ float s_p[NN];    // pred
    __shared__ float s_is[NN];   // invS per row (this block's rows only)
    __shared__ float s_max[4];
    __shared__ float s_cnt[4];
    __shared__ float s_acc[4];

    const int b     = blockIdx.x / CHUNKS;
    const int chunk = blockIdx.x % CHUNKS;
    const int tid   = threadIdx.x;
    const int lane  = tid & 63;
    const int wave  = tid >> 6;

    // ---- stage inputs, fold batch max + valid count ----
    float lmax = -1.0f, lcnt = 0.0f;
    #pragma unroll
    for (int k = 0; k < NN / 256; ++k) {
        int j = tid + 256 * k;
        float p = pred[b * NN + j];
        float t = target[b * NN + j];
        int   v = valid[b * NN + j];
        float tm = v ? t : -1.0f;
        s_p[j]  = p;
        s_e[j]  = __expf(p);
        s_tm[j] = tm;
        lmax = fmaxf(lmax, tm);
        lcnt += v ? 1.0f : 0.0f;
    }
    #pragma unroll
    for (int off = 32; off; off >>= 1) {
        lmax = fmaxf(lmax, __shfl_xor(lmax, off, 64));
        lcnt += __shfl_xor(lcnt, off, 64);
    }
    if (lane == 0) { s_max[wave] = lmax; s_cnt[wave] = lcnt; }
    __syncthreads();
    const float bmax = fmaxf(fmaxf(s_max[0], s_max[1]), fmaxf(s_max[2], s_max[3]));
    const float bcnt = s_cnt[0] + s_cnt[1] + s_cnt[2] + s_cnt[3];
    const float batch_valid = (bcnt >= 2.0f) ? 1.0f : 0.0f;

    // ---- preload lane-owned columns into registers (once per block) ----
    float tj[8], e0[8];
    #pragma unroll
    for (int k = 0; k < 8; ++k) {
        tj[k] = s_tm[lane + 64 * k];
        e0[k] = s_e[lane + 64 * k];
    }

    // ---- O(N^2) row loop ----
    float acc = 0.0f;
    const int row0 = chunk * RPB + wave * RPW;
    for (int r = 0; r < RPW; ++r) {
        const int i = row0 + r;
        const float Ti = s_tm[i];                   // wave-uniform broadcast
        if (!(Ti > 0.0f && Ti < bmax)) continue;    // not eliminated (uniform)

        float em[8];
        float S = 0.0f;
        #pragma unroll
        for (int k = 0; k < 8; ++k) {
            float x = (tj[k] >= Ti) ? e0[k] : 0.0f;
            em[k] = x;
            S += x;
        }
        #pragma unroll
        for (int off = 32; off; off >>= 1) S += __shfl_xor(S, off, 64);
        const float invS = __builtin_amdgcn_rcpf(S);
        if (lane == 0) s_is[i] = invS;

        float prod = 1.0f;
        #pragma unroll
        for (int k = 0; k < 8; ++k)
            prod *= fmaxf(fmaf(-em[k], invS, ONEP), TWOEPS);
        acc -= __logf(prod);
    }

    // ---- per-row epilogue: part1 + diagonal correction (same wave's rows) ----
    if (lane < RPW) {
        const int i = row0 + lane;
        const float Ti = s_tm[i];
        if (Ti > 0.0f && Ti < bmax) {
            float invS = s_is[i];
            float part1 = -__logf(invS) - s_p[i];
            float pii = s_e[i] * invS;
            float qi = fmaxf(ONEP - pii, TWOEPS);
            acc += part1 + __logf(qi);
        }
    }

    // ---- block reduce; write (not atomic) partials to distinct slots ----
    #pragma unroll
    for (int off = 32; off; off >>= 1) acc += __shfl_xor(acc, off, 64);
    if (lane == 0) s_acc[wave] = acc;
    __syncthreads();
    if (tid == 0) {
        ws[blockIdx.x] = (s_acc[0] + s_acc[1] + s_acc[2] + s_acc[3]) * batch_valid;
        if (chunk == 0) ws[GRID + b] = batch_valid;
    }
}

// Single 256-thread block: sum GRID partials and BB valid flags, divide.
__global__ __launch_bounds__(256) void cox_final(const float* __restrict__ ws,
                                                 float* __restrict__ out) {
    __shared__ float s_tot[4];
    __shared__ float s_cnt[4];
    const int tid  = threadIdx.x;
    const int lane = tid & 63;
    const int wave = tid >> 6;

    float tot = 0.0f;
    #pragma unroll
    for (int k = 0; k < GRID / 256; ++k) tot += ws[tid + 256 * k];
    float cnt = (tid < BB) ? ws[GRID + tid] : 0.0f;

    #pragma unroll
    for (int off = 32; off; off >>= 1) {
        tot += __shfl_xor(tot, off, 64);
        cnt += __shfl_xor(cnt, off, 64);
    }
    if (lane == 0) { s_tot[wave] = tot; s_cnt[wave] = cnt; }
    __syncthreads();
    if (tid == 0) {
        float T = s_tot[0] + s_tot[1] + s_tot[2] + s_tot[3];
        float C = s_cnt[0] + s_cnt[1] + s_cnt[2] + s_cnt[3];
        out[0] = T / fmaxf(C, 1.0f);
    }
}

extern "C" void kernel_launch(void* const* d_in, const int* in_sizes, int n_in,
                              void* d_out, int out_size, void* d_ws, size_t ws_size,
                              hipStream_t stream) {
    const float* pred   = (const float*)d_in[0];
    const float* target = (const float*)d_in[1];
    const int*   valid  = (const int*)d_in[2];
    float* out = (float*)d_out;
    float* ws  = (float*)d_ws;

    cox_main<<<GRID, 256, 0, stream>>>(pred, target, valid, ws);
    cox_final<<<1, 256, 0, stream>>>(ws, out);
}

// Round 7
// 68.954 us; speedup vs baseline: 1.6109x; 1.0048x over previous
//
#include <hip/hip_runtime.h>
#include <math.h>

#define BB 128
#define NN 512
#define CHUNKS 8
#define RPB (NN / CHUNKS)   // 64 rows per block
#define RPW (RPB / 4)       // 16 rows per wave
#define GRID (BB * CHUNKS)
#define EPSF 1e-7f
#define ONEP (1.0f + EPSF)
#define TWOEPS (2.0f * EPSF)

// One block = (batch b, 64-row chunk). 256 threads = 4 waves, 16 rows/wave,
// processed 2 rows at a time (ILP on the shuffle/rcp/log chains).
//
// Identities (pred ~ N(0,1) -> no max-subtraction needed):
//   e_j = exp(pred_j) row-independent, computed once per block.
//   S_i = sum_{T_j >= T_i} e_j
//   row loss = part1 + part2
//            = [log S_i - p_i] + sum_{j in risk, j != i} -log q_ij,
//     q_ij = max(1+eps - e_j/S_i, 2eps)
//   Folded into ONE log per row-lane: owner lane (i&63) multiplies its
//   partial product by  invS * e_i / q_ii  so that
//     -log(prod * invS * e_i / q_ii) = -log(prod) + log S_i - p_i + log q_ii
//   (removes diagonal term and adds part1; log e_i == p_i to ~1e-7 rel).
//   Dead rows (not eliminated) are branch-free: Ti := +INF zeroes all em,
//   S := 1 keeps rcp/log finite, and the contribution is * elim(=0).
//
// Partials are WRITTEN to distinct ws slots (no memset, no atomics, no fence;
// R4 showed device-scope fences force L2 writeback of the 268MB poisoned ws):
//   ws[0..GRID)        block partial sums (already scaled by batch_valid)
//   ws[GRID..GRID+BB)  per-batch valid flag (written by chunk==0 block)
__global__ __launch_bounds__(256) void cox_main(const float* __restrict__ pred,
                                                const float* __restrict__ target,
                                                const int* __restrict__ valid,
                                                float* __restrict__ ws) {
    __shared__ float s_e[NN];    // exp(pred)
    __shared__ float s_tm[NN];   // masked target
    __shared__ float s_max[4];
    __shared__ float s_cnt[4];
    __shared__ float s_acc[4];

    const int b     = blockIdx.x / CHUNKS;
    const int chunk = blockIdx.x % CHUNKS;
    const int tid   = threadIdx.x;
    const int lane  = tid & 63;
    const int wave  = tid >> 6;

    // ---- stage inputs, fold batch max + valid count ----
    float lmax = -1.0f, lcnt = 0.0f;
    #pragma unroll
    for (int k = 0; k < NN / 256; ++k) {
        int j = tid + 256 * k;
        float p = pred[b * NN + j];
        float t = target[b * NN + j];
        int   v = valid[b * NN + j];
        float tm = v ? t : -1.0f;
        s_e[j]  = __expf(p);
        s_tm[j] = tm;
        lmax = fmaxf(lmax, tm);
        lcnt += v ? 1.0f : 0.0f;
    }
    #pragma unroll
    for (int off = 32; off; off >>= 1) {
        lmax = fmaxf(lmax, __shfl_xor(lmax, off, 64));
        lcnt += __shfl_xor(lcnt, off, 64);
    }
    if (lane == 0) { s_max[wave] = lmax; s_cnt[wave] = lcnt; }
    __syncthreads();
    const float bmax = fmaxf(fmaxf(s_max[0], s_max[1]), fmaxf(s_max[2], s_max[3]));
    const float bcnt = s_cnt[0] + s_cnt[1] + s_cnt[2] + s_cnt[3];
    const float batch_valid = (bcnt >= 2.0f) ? 1.0f : 0.0f;

    // ---- preload lane-owned columns into registers (once per block) ----
    float tj[8], e0[8];
    #pragma unroll
    for (int k = 0; k < 8; ++k) {
        tj[k] = s_tm[lane + 64 * k];
        e0[k] = s_e[lane + 64 * k];
    }

    // ---- O(N^2) row loop, 2 rows per iteration ----
    float acc = 0.0f;
    const int row0 = chunk * RPB + wave * RPW;
    for (int r0 = 0; r0 < RPW; r0 += 2) {
        float Ti[2], ei[2], elim[2], S[2], prod[2];
        float em[2][8];
        #pragma unroll
        for (int rr = 0; rr < 2; ++rr) {
            const int i = row0 + r0 + rr;
            float t = s_tm[i];
            bool el = (t > 0.0f && t < bmax);
            elim[rr] = el ? 1.0f : 0.0f;
            Ti[rr]   = el ? t : INFINITY;   // dead row: em all-zero
            ei[rr]   = s_e[i];
            S[rr]    = 0.0f;
            prod[rr] = 1.0f;
        }
        #pragma unroll
        for (int k = 0; k < 8; ++k) {
            #pragma unroll
            for (int rr = 0; rr < 2; ++rr) {
                float x = (tj[k] >= Ti[rr]) ? e0[k] : 0.0f;
                em[rr][k] = x;
                S[rr] += x;
            }
        }
        #pragma unroll
        for (int off = 32; off; off >>= 1) {
            #pragma unroll
            for (int rr = 0; rr < 2; ++rr)
                S[rr] += __shfl_xor(S[rr], off, 64);
        }
        float invS[2], F[2];
        #pragma unroll
        for (int rr = 0; rr < 2; ++rr) {
            float Sc = (elim[rr] != 0.0f) ? S[rr] : 1.0f;  // dead row: finite
            float is = __builtin_amdgcn_rcpf(Sc);
            invS[rr] = is;
            float qii = fmaxf(fmaf(-ei[rr], is, ONEP), TWOEPS);  // wave-uniform
            F[rr] = is * ei[rr] * __builtin_amdgcn_rcpf(qii);
        }
        #pragma unroll
        for (int k = 0; k < 8; ++k) {
            #pragma unroll
            for (int rr = 0; rr < 2; ++rr)
                prod[rr] *= fmaxf(fmaf(-em[rr][k], invS[rr], ONEP), TWOEPS);
        }
        #pragma unroll
        for (int rr = 0; rr < 2; ++rr) {
            const int i = row0 + r0 + rr;
            float mul = (lane == (i & 63)) ? F[rr] : 1.0f;  // owner-lane fold
            prod[rr] *= mul;
            acc -= elim[rr] * __logf(prod[rr]);
        }
    }

    // ---- block reduce; write (not atomic) partials to distinct slots ----
    #pragma unroll
    for (int off = 32; off; off >>= 1) acc += __shfl_xor(acc, off, 64);
    if (lane == 0) s_acc[wave] = acc;
    __syncthreads();
    if (tid == 0) {
        ws[blockIdx.x] = (s_acc[0] + s_acc[1] + s_acc[2] + s_acc[3]) * batch_valid;
        if (chunk == 0) ws[GRID + b] = batch_valid;
    }
}

// Single 256-thread block: sum GRID partials and BB valid flags, divide.
__global__ __launch_bounds__(256) void cox_final(const float* __restrict__ ws,
                                                 float* __restrict__ out) {
    __shared__ float s_tot[4];
    __shared__ float s_cnt[4];
    const int tid  = threadIdx.x;
    const int lane = tid & 63;
    const int wave = tid >> 6;

    float tot = 0.0f;
    #pragma unroll
    for (int k = 0; k < GRID / 256; ++k) tot += ws[tid + 256 * k];
    float cnt = (tid < BB) ? ws[GRID + tid] : 0.0f;

    #pragma unroll
    for (int off = 32; off; off >>= 1) {
        tot += __shfl_xor(tot, off, 64);
        cnt += __shfl_xor(cnt, off, 64);
    }
    if (lane == 0) { s_tot[wave] = tot; s_cnt[wave] = cnt; }
    __syncthreads();
    if (tid == 0) {
        float T = s_tot[0] + s_tot[1] + s_tot[2] + s_tot[3];
        float C = s_cnt[0] + s_cnt[1] + s_cnt[2] + s_cnt[3];
        out[0] = T / fmaxf(C, 1.0f);
    }
}

extern "C" void kernel_launch(void* const* d_in, const int* in_sizes, int n_in,
                              void* d_out, int out_size, void* d_ws, size_t ws_size,
                              hipStream_t stream) {
    const float* pred   = (const float*)d_in[0];
    const float* target = (const float*)d_in[1];
    const int*   valid  = (const int*)d_in[2];
    float* out = (float*)d_out;
    float* ws  = (float*)d_ws;

    cox_main<<<GRID, 256, 0, stream>>>(pred, target, valid, ws);
    cox_final<<<1, 256, 0, stream>>>(ws, out);
}